// Round 2
// baseline (233.090 us; speedup 1.0000x reference)
//
#include <hip/hip_runtime.h>

typedef _Float16 v8h __attribute__((ext_vector_type(8)));
typedef _Float16 v4h __attribute__((ext_vector_type(4)));
typedef float    v4f __attribute__((ext_vector_type(4)));

#define MFMA16(a, b, c) __builtin_amdgcn_mfma_f32_16x16x32_f16((a), (b), (c), 0, 0, 0)

// Weight-fragment table in d_ws: 154 fragments, layout [frag][lane] of 8 x f16 (16B).
// Non-zero 32(k) x 16(n) tiles of the 480x480 block-diagonal Wbig:
//   ot 0..7   (cols   0..127): kt 0..3   fbase = ot*4
//   ot 8..19  (cols 128..319): kt 4..9   fbase = 32 + (ot-8)*6
//   ot 20..29 (cols 320..479): kt 10..14 fbase = 104 + (ot-20)*5
// Fragment element convention (consistent for A and B): lane l, elem e holds
// k = kt*32 + (l>>4)*8 + e;  B: n = ot*16 + (l&15);  A: m = l&15.

__global__ void build_frags_k(const float* __restrict__ W0, const float* __restrict__ W1,
                              const float* __restrict__ W2, v8h* __restrict__ frag) {
  const int f = blockIdx.x;
  const int lane = threadIdx.x;
  int ot, kt;
  if (f < 32)       { ot = f >> 2;           kt = f & 3; }
  else if (f < 104) { int q = f - 32;  ot = 8 + q / 6;  kt = 4 + q % 6; }
  else              { int q = f - 104; ot = 20 + q / 5; kt = 10 + q % 5; }
  const int n  = ot * 16 + (lane & 15);
  const int kb = kt * 32 + (lane >> 4) * 8;
  v8h v;
#pragma unroll
  for (int e = 0; e < 8; ++e) {
    const int k = kb + e;
    float wv = 0.0f;
    if (k < 128) {
      if (n < 128) wv = W0[k * 128 + n] * 0.08838834764831845f;           // 1/sqrt(128)
    } else if (k < 320) {
      if (n >= 128 && n < 320) {
        const int i = k - 128, o = n - 128;
        if (i % 3 == o % 3) wv = W1[(i / 3) * 64 + (o / 3)] * 0.125f;     // 1/sqrt(64)
      }
    } else {
      if (n >= 320) {
        const int i = k - 320, o = n - 320;
        if (i % 5 == o % 5) wv = W2[(i / 5) * 32 + (o / 5)] * 0.17677669529663687f; // 1/sqrt(32)
      }
    }
    v[e] = (_Float16)wv;
  }
  frag[f * 64 + lane] = v;
}

// Persistent blocks: 256 threads (4 waves), 32 rows per tile, 32KB LDS
// -> 4 blocks/CU resident. Each block owns a contiguous chunk of tiles and
// register-prefetches tile t+1 during tile t's MFMA/store phase (T14).
// Wave = (slab 0..1) x (ot-parity 0..1); per wave: 16 rows, 15 of 30 col-tiles.
__global__ __launch_bounds__(256, 4) void irrep_linear_k(
    const float* __restrict__ x, const v8h* __restrict__ frag, float* __restrict__ out,
    int base_tpb, int rem, int n_tiles) {
  __shared__ __align__(16) unsigned char sm[32 * 1024];
  const int t = threadIdx.x;
  const int b = blockIdx.x;
  // chunked assignment: first `rem` blocks get base_tpb+1 tiles
  const int t0 = b * base_tpb + (b < rem ? b : rem);
  const int t1 = t0 + base_tpb + (b < rem ? 1 : 0);
  if (t0 >= n_tiles) return;

  const float4* xv = reinterpret_cast<const float4*>(x);
  float4 rg[15];
  {
    const float4* p = xv + (size_t)t0 * 3840;
#pragma unroll
    for (int i = 0; i < 15; ++i) rg[i] = p[i * 256 + t];
  }

  const int wid  = t >> 6;
  const int lane = t & 63;
  const int slab = wid >> 1;     // 16-row slab within the 32-row tile
  const int par  = wid & 1;      // ot parity
  const int r16  = lane & 15;
  const int g    = lane >> 4;
  const unsigned arow  = (unsigned)(slab * 16 + r16);
  const unsigned abase = arow * 1024u + (unsigned)g * 16u;
  const unsigned swz   = (arow & 7u) << 4;
  const unsigned char* smc = sm;
#define LDA(kt) (*reinterpret_cast<const v8h*>(smc + ((abase + (unsigned)(kt) * 64u) ^ swz)))

  for (int tt = t0; tt < t1; ++tt) {
    // ---- convert + write LDS (consumes rg) ----
#pragma unroll
    for (int i = 0; i < 15; ++i) {
      const int idx = i * 256 + t;          // 0..3839 over the 32x480 tile
      const int r   = idx / 120;
      const int c4  = idx - r * 120;
      const unsigned off = (unsigned)r * 1024u + (((unsigned)c4 * 8u) ^ ((unsigned)(r & 7) << 4));
      v4h v;
      v[0] = (_Float16)rg[i].x; v[1] = (_Float16)rg[i].y;
      v[2] = (_Float16)rg[i].z; v[3] = (_Float16)rg[i].w;
      *reinterpret_cast<v4h*>(sm + off) = v;
    }
    __syncthreads();   // drains lgkm -> rg is dead, safe to reload

    // ---- prefetch next tile into the same registers (overlaps compute) ----
    if (tt + 1 < t1) {
      const float4* p = xv + (size_t)(tt + 1) * 3840;
#pragma unroll
      for (int i = 0; i < 15; ++i) rg[i] = p[i * 256 + t];
    }

    // ---- compute + store ----
    float* const obase = out + ((size_t)tt * 32 + (size_t)slab * 16 + (size_t)g * 4) * 480 + r16;

    {  // cols 0..127, K-tiles 0..3
      const v8h a0 = LDA(0), a1 = LDA(1), a2 = LDA(2), a3 = LDA(3);
      for (int ot = par; ot < 8; ot += 2) {
        const v8h* bp = frag + ot * 4 * 64 + lane;
        v4f acc = {0.f, 0.f, 0.f, 0.f};
        acc = MFMA16(a0, bp[0],   acc);
        acc = MFMA16(a1, bp[64],  acc);
        acc = MFMA16(a2, bp[128], acc);
        acc = MFMA16(a3, bp[192], acc);
        float* p = obase + ot * 16;
        p[0] = acc[0]; p[480] = acc[1]; p[960] = acc[2]; p[1440] = acc[3];
      }
    }
    {  // cols 128..319, K-tiles 4..9
      const v8h a4 = LDA(4), a5 = LDA(5), a6 = LDA(6), a7 = LDA(7), a8 = LDA(8), a9 = LDA(9);
      for (int ot = 8 + par; ot < 20; ot += 2) {
        const v8h* bp = frag + (32 + (ot - 8) * 6) * 64 + lane;
        v4f acc = {0.f, 0.f, 0.f, 0.f};
        acc = MFMA16(a4, bp[0],   acc);
        acc = MFMA16(a5, bp[64],  acc);
        acc = MFMA16(a6, bp[128], acc);
        acc = MFMA16(a7, bp[192], acc);
        acc = MFMA16(a8, bp[256], acc);
        acc = MFMA16(a9, bp[320], acc);
        float* p = obase + ot * 16;
        p[0] = acc[0]; p[480] = acc[1]; p[960] = acc[2]; p[1440] = acc[3];
      }
    }
    {  // cols 320..479, K-tiles 10..14
      const v8h aA = LDA(10), aB = LDA(11), aC = LDA(12), aD = LDA(13), aE = LDA(14);
      for (int ot = 20 + par; ot < 30; ot += 2) {
        const v8h* bp = frag + (104 + (ot - 20) * 5) * 64 + lane;
        v4f acc = {0.f, 0.f, 0.f, 0.f};
        acc = MFMA16(aA, bp[0],   acc);
        acc = MFMA16(aB, bp[64],  acc);
        acc = MFMA16(aC, bp[128], acc);
        acc = MFMA16(aD, bp[192], acc);
        acc = MFMA16(aE, bp[256], acc);
        float* p = obase + ot * 16;
        p[0] = acc[0]; p[480] = acc[1]; p[960] = acc[2]; p[1440] = acc[3];
      }
    }
    __syncthreads();   // LDS consumed; next iter may overwrite
  }
#undef LDA
}

extern "C" void kernel_launch(void* const* d_in, const int* in_sizes, int n_in,
                              void* d_out, int out_size, void* d_ws, size_t ws_size,
                              hipStream_t stream) {
  const float* x  = (const float*)d_in[0];
  const float* W0 = (const float*)d_in[1];
  const float* W1 = (const float*)d_in[2];
  const float* W2 = (const float*)d_in[3];
  float* out = (float*)d_out;
  v8h* frag = (v8h*)d_ws;   // 154 * 64 * 16 B = 157,696 B

  build_frags_k<<<154, 64, 0, stream>>>(W0, W1, W2, frag);

  const int N = in_sizes[0] / 480;          // 200000
  const int n_tiles = N / 32;               // 6250 (exact)
  const int nblk = 1024;                    // 4 blocks/CU x 256 CUs
  const int base_tpb = n_tiles / nblk;      // 6
  const int rem = n_tiles - base_tpb * nblk;  // 106
  irrep_linear_k<<<nblk, 256, 0, stream>>>(x, frag, out, base_tpb, rem, n_tiles);
}

// Round 3
// 210.791 us; speedup vs baseline: 1.1058x; 1.1058x over previous
//
#include <hip/hip_runtime.h>

typedef _Float16 v8h __attribute__((ext_vector_type(8)));
typedef float    v4f __attribute__((ext_vector_type(4)));

#define MFMA16(a, b, c) __builtin_amdgcn_mfma_f32_16x16x32_f16((a), (b), (c), 0, 0, 0)

// Weight-fragment table in d_ws: 154 fragments, layout [frag][lane] of 8 x f16 (16B).
// Non-zero 32(k) x 16(n) tiles of the 480x480 block-diagonal Wbig:
//   ot 0..7   (cols   0..127): kt 0..3   fbase = ot*4
//   ot 8..19  (cols 128..319): kt 4..9   fbase = 32 + (ot-8)*6
//   ot 20..29 (cols 320..479): kt 10..14 fbase = 104 + (ot-20)*5
// Fragment element convention (consistent for A and B): lane l, elem e holds
// k = kt*32 + (l>>4)*8 + e;  B: n = ot*16 + (l&15);  A: m = l&15.
// C/D (HW-verified): lane l, reg j -> row (l>>4)*4 + j, col l&15.

__global__ void build_frags_k(const float* __restrict__ W0, const float* __restrict__ W1,
                              const float* __restrict__ W2, v8h* __restrict__ frag) {
  const int f = blockIdx.x;
  const int lane = threadIdx.x;
  int ot, kt;
  if (f < 32)       { ot = f >> 2;           kt = f & 3; }
  else if (f < 104) { int q = f - 32;  ot = 8 + q / 6;  kt = 4 + q % 6; }
  else              { int q = f - 104; ot = 20 + q / 5; kt = 10 + q % 5; }
  const int n  = ot * 16 + (lane & 15);
  const int kb = kt * 32 + (lane >> 4) * 8;
  v8h v;
#pragma unroll
  for (int e = 0; e < 8; ++e) {
    const int k = kb + e;
    float wv = 0.0f;
    if (k < 128) {
      if (n < 128) wv = W0[k * 128 + n] * 0.08838834764831845f;           // 1/sqrt(128)
    } else if (k < 320) {
      if (n >= 128 && n < 320) {
        const int i = k - 128, o = n - 128;
        if (i % 3 == o % 3) wv = W1[(i / 3) * 64 + (o / 3)] * 0.125f;     // 1/sqrt(64)
      }
    } else {
      if (n >= 320) {
        const int i = k - 320, o = n - 320;
        if (i % 5 == o % 5) wv = W2[(i / 5) * 32 + (o / 5)] * 0.17677669529663687f; // 1/sqrt(32)
      }
    }
    v[e] = (_Float16)wv;
  }
  frag[f * 64 + lane] = v;
}

// No LDS, no barriers: each wave owns 16 rows end-to-end. A-fragments are
// loaded per-lane straight from global (lane l: rows l&15, k-bytes
// [kt*128+(l>>4)*32, +32) = two aligned float4), converted f32->f16 in
// registers. B-fragments stream from the L2-resident table. Waves are fully
// independent -> the HBM read stream never convoy-stalls.
__global__ __launch_bounds__(256, 3) void irrep_linear_k(
    const float* __restrict__ x, const v8h* __restrict__ frag, float* __restrict__ out) {
  const int t    = threadIdx.x;
  const int lane = t & 63;
  const int wid  = t >> 6;
  const size_t wt = (size_t)blockIdx.x * 4 + wid;    // wave-tile 0..12499 (16 rows each)
  const int r16 = lane & 15;
  const int g   = lane >> 4;

  const char* xp = (const char*)x + (wt * 16 + (size_t)r16) * 1920 + (size_t)g * 32;

  v8h a[15];
  // batch 1: kt 0..7 (16 loads in flight), convert
  {
    float4 rg[16];
#pragma unroll
    for (int kt = 0; kt < 8; ++kt) {
      rg[2 * kt]     = *reinterpret_cast<const float4*>(xp + kt * 128);
      rg[2 * kt + 1] = *reinterpret_cast<const float4*>(xp + kt * 128 + 16);
    }
#pragma unroll
    for (int kt = 0; kt < 8; ++kt) {
      v8h v;
      v[0] = (_Float16)rg[2 * kt].x;     v[1] = (_Float16)rg[2 * kt].y;
      v[2] = (_Float16)rg[2 * kt].z;     v[3] = (_Float16)rg[2 * kt].w;
      v[4] = (_Float16)rg[2 * kt + 1].x; v[5] = (_Float16)rg[2 * kt + 1].y;
      v[6] = (_Float16)rg[2 * kt + 1].z; v[7] = (_Float16)rg[2 * kt + 1].w;
      a[kt] = v;
    }
  }
  // batch 2: kt 8..14 (14 loads in flight), convert
  {
    float4 rg[14];
#pragma unroll
    for (int kt = 8; kt < 15; ++kt) {
      rg[2 * (kt - 8)]     = *reinterpret_cast<const float4*>(xp + kt * 128);
      rg[2 * (kt - 8) + 1] = *reinterpret_cast<const float4*>(xp + kt * 128 + 16);
    }
#pragma unroll
    for (int kt = 8; kt < 15; ++kt) {
      v8h v;
      v[0] = (_Float16)rg[2 * (kt - 8)].x;     v[1] = (_Float16)rg[2 * (kt - 8)].y;
      v[2] = (_Float16)rg[2 * (kt - 8)].z;     v[3] = (_Float16)rg[2 * (kt - 8)].w;
      v[4] = (_Float16)rg[2 * (kt - 8) + 1].x; v[5] = (_Float16)rg[2 * (kt - 8) + 1].y;
      v[6] = (_Float16)rg[2 * (kt - 8) + 1].z; v[7] = (_Float16)rg[2 * (kt - 8) + 1].w;
      a[kt] = v;
    }
  }

  float* const obase = out + (wt * 16 + (size_t)g * 4) * 480 + r16;

  // cols 0..127, K-tiles 0..3
#pragma unroll
  for (int ot = 0; ot < 8; ++ot) {
    const v8h* bp = frag + ot * 4 * 64 + lane;
    v4f acc = {0.f, 0.f, 0.f, 0.f};
    acc = MFMA16(a[0], bp[0],   acc);
    acc = MFMA16(a[1], bp[64],  acc);
    acc = MFMA16(a[2], bp[128], acc);
    acc = MFMA16(a[3], bp[192], acc);
    float* p = obase + ot * 16;
    __builtin_nontemporal_store(acc[0], p);
    __builtin_nontemporal_store(acc[1], p + 480);
    __builtin_nontemporal_store(acc[2], p + 960);
    __builtin_nontemporal_store(acc[3], p + 1440);
  }
  // cols 128..319, K-tiles 4..9
#pragma unroll
  for (int ot = 8; ot < 20; ++ot) {
    const v8h* bp = frag + (32 + (ot - 8) * 6) * 64 + lane;
    v4f acc = {0.f, 0.f, 0.f, 0.f};
    acc = MFMA16(a[4], bp[0],   acc);
    acc = MFMA16(a[5], bp[64],  acc);
    acc = MFMA16(a[6], bp[128], acc);
    acc = MFMA16(a[7], bp[192], acc);
    acc = MFMA16(a[8], bp[256], acc);
    acc = MFMA16(a[9], bp[320], acc);
    float* p = obase + ot * 16;
    __builtin_nontemporal_store(acc[0], p);
    __builtin_nontemporal_store(acc[1], p + 480);
    __builtin_nontemporal_store(acc[2], p + 960);
    __builtin_nontemporal_store(acc[3], p + 1440);
  }
  // cols 320..479, K-tiles 10..14
#pragma unroll
  for (int ot = 20; ot < 30; ++ot) {
    const v8h* bp = frag + (104 + (ot - 20) * 5) * 64 + lane;
    v4f acc = {0.f, 0.f, 0.f, 0.f};
    acc = MFMA16(a[10], bp[0],   acc);
    acc = MFMA16(a[11], bp[64],  acc);
    acc = MFMA16(a[12], bp[128], acc);
    acc = MFMA16(a[13], bp[192], acc);
    acc = MFMA16(a[14], bp[256], acc);
    float* p = obase + ot * 16;
    __builtin_nontemporal_store(acc[0], p);
    __builtin_nontemporal_store(acc[1], p + 480);
    __builtin_nontemporal_store(acc[2], p + 960);
    __builtin_nontemporal_store(acc[3], p + 1440);
  }
}

extern "C" void kernel_launch(void* const* d_in, const int* in_sizes, int n_in,
                              void* d_out, int out_size, void* d_ws, size_t ws_size,
                              hipStream_t stream) {
  const float* x  = (const float*)d_in[0];
  const float* W0 = (const float*)d_in[1];
  const float* W1 = (const float*)d_in[2];
  const float* W2 = (const float*)d_in[3];
  float* out = (float*)d_out;
  v8h* frag = (v8h*)d_ws;   // 154 * 64 * 16 B = 157,696 B

  build_frags_k<<<154, 64, 0, stream>>>(W0, W1, W2, frag);

  const int N = in_sizes[0] / 480;      // 200000
  const int nblk = N / 64;              // 3125: 4 wave-tiles (16 rows) per block
  irrep_linear_k<<<nblk, 256, 0, stream>>>(x, frag, out);
}